// Round 1
// baseline (53697.150 us; speedup 1.0000x reference)
//
#include <hip/hip_runtime.h>
#include <math.h>

#define NLFULL 504
#define REAL_NL 500
#define BATCH 2048
#define NZ 50
#define NC 21
#define GHID 512
#define EPSB 1e-5f

// =============================== upsample ==================================
// One block per (b, strip of 16 t0). Stages: dense -> dc0 -> dc1 -> dc2,
// LDS ping-pong (bufA: u then w, bufB: v then h written straight to hseq).
__global__ __launch_bounds__(512) void upsample_kernel(
    const float* __restrict__ z, const float* __restrict__ dW, const float* __restrict__ db,
    const float* __restrict__ W0, const float* __restrict__ g0, const float* __restrict__ bb0,
    const float* __restrict__ m0, const float* __restrict__ v0, const float* __restrict__ al0,
    const float* __restrict__ W1, const float* __restrict__ g1, const float* __restrict__ bb1,
    const float* __restrict__ m1, const float* __restrict__ v1, const float* __restrict__ al1,
    const float* __restrict__ W2, const float* __restrict__ g2, const float* __restrict__ bb2,
    const float* __restrict__ m2, const float* __restrict__ v2, const float* __restrict__ al2,
    float* __restrict__ hseq)
{
    __shared__ float bufA[5712];   // u: [336][17]   then w: [84][65]
    __shared__ float bufB[5544];   // v: [168][33]   (h written to global)
    __shared__ float zl[52];

    const int b   = blockIdx.x;
    const int ta  = blockIdx.y * 16;
    const int nt0 = min(16, 63 - ta);
    const int tid = threadIdx.x;

    if (tid < NZ) zl[tid] = z[b * NZ + tid];
    __syncthreads();

    // ---- stage A: dense  u[c][tt] = z . dW_row ----
    for (int i = tid; i < 336 * nt0; i += 512) {
        int c = i % 336, tt = i / 336;
        int row = c * 63 + ta + tt;
        const float* wr = dW + (size_t)row * NZ;
        float s = db[row];
        #pragma unroll
        for (int n = 0; n < NZ; ++n) s += zl[n] * wr[n];
        bufA[c * 17 + tt] = s;
    }
    __syncthreads();

    const float a0 = al0[0], a1 = al1[0], a2 = al2[0];

    // ---- stage B: dc0 336->168, T 16->32, BN+PReLU ----
    for (int i = tid; i < 168 * 2 * nt0; i += 512) {
        int o = i % 168, tt1 = i / 168;
        int tt = tt1 >> 1, k = tt1 & 1;
        const float* wp = W0 + o * 2 + k;       // stride 336 per c
        float s = 0.f;
        for (int c = 0; c < 336; ++c) s += bufA[c * 17 + tt] * wp[c * 336];
        float sc = g0[o] / sqrtf(v0[o] + EPSB);
        s = (s - m0[o]) * sc + bb0[o];
        s = (s >= 0.f) ? s : a0 * s;
        bufB[o * 33 + tt1] = s;
    }
    __syncthreads();

    // ---- stage C: dc1 168->84, T 32->64 ----
    for (int i = tid; i < 84 * 4 * nt0; i += 512) {
        int o = i % 84, tt2 = i / 84;
        int tt1 = tt2 >> 1, k = tt2 & 1;
        const float* wp = W1 + o * 2 + k;       // stride 168 per c
        float s = 0.f;
        for (int c = 0; c < 168; ++c) s += bufB[c * 33 + tt1] * wp[c * 168];
        float sc = g1[o] / sqrtf(v1[o] + EPSB);
        s = (s - m1[o]) * sc + bb1[o];
        s = (s >= 0.f) ? s : a1 * s;
        bufA[o * 65 + tt2] = s;
    }
    __syncthreads();

    // ---- stage D: dc2 84->42, T 64->128, write hseq[t][b][o] ----
    for (int i = tid; i < 42 * 8 * nt0; i += 512) {
        int o = i % 42, tt3 = i / 42;
        int tt2 = tt3 >> 1, k = tt3 & 1;
        const float* wp = W2 + o * 2 + k;       // stride 84 per c
        float s = 0.f;
        for (int c = 0; c < 84; ++c) s += bufA[c * 65 + tt2] * wp[c * 84];
        float sc = g2[o] / sqrtf(v2[o] + EPSB);
        s = (s - m2[o]) * sc + bb2[o];
        s = (s >= 0.f) ? s : a2 * s;
        int t3 = 8 * ta + tt3;
        hseq[(size_t)t3 * (BATCH * 42) + b * 42 + o] = s;
    }
}

// ================= table: gi-contribution of one-hot px =====================
// table[e][jg] = sum_j' (w_px[j',e] + b_px[j']) * w_ih[jg, 42+j'] + b_ih[jg]
// e == NC (21): the zeros-x1h entry (px = b_px only).
__global__ void table_kernel(const float* __restrict__ w_px, const float* __restrict__ b_px,
                             const float* __restrict__ w_ih, const float* __restrict__ b_ih,
                             float* __restrict__ table)
{
    int i = blockIdx.x * 256 + threadIdx.x;
    if (i >= 22 * 1536) return;
    int e = i / 1536, jg = i % 1536;
    const float* wih = w_ih + jg * 63 + 42;
    float s = b_ih[jg];
    #pragma unroll
    for (int jp = 0; jp < NC; ++jp) {
        float px = b_px[jp] + (e < NC ? w_px[jp * NC + e] : 0.f);
        s += px * wih[jp];
    }
    table[i] = s;
}

// ============================ init h0, idx ==================================
__global__ void init_kernel(float* __restrict__ hA, int* __restrict__ idx)
{
    int i = blockIdx.x * 256 + threadIdx.x;
    if (i < BATCH * GHID) hA[i] = 0.f;
    if (i < BATCH) idx[i] = NC;   // zeros-x1h table entry
}

// ============================ GRU gates =====================================
// BM=64 (batch), BN=32 (hidden cols), BK=32; 3 gates. 256 thr: 16x16,
// micro-tile 4 rows x 2 cols x 3 gates, separate H (w_hh) and I (w_ih) accums.
__global__ __launch_bounds__(256) void gru_gates(
    const float* __restrict__ h_prev, const float* __restrict__ ht,   // hseq + t*B*42
    const int* __restrict__ idx, const float* __restrict__ table,
    const float* __restrict__ w_hh, const float* __restrict__ w_ih,
    const float* __restrict__ b_hh, float* __restrict__ h_new)
{
    __shared__ float hs[32 * 68];          // [k][m], stride 68 (16B-aligned, low conflict)
    __shared__ float wsm[3][32 * 34];      // [g][k][n], stride 34

    const int tid = threadIdx.x;
    const int n0 = blockIdx.x * 32;
    const int m0 = blockIdx.y * 64;
    const int tn = tid & 15, tm = tid >> 4;

    float accH[3][4][2] = {{{0.f}}};
    float accI[3][4][2] = {{{0.f}}};

    for (int k0 = 0; k0 < GHID; k0 += 32) {
        // stage h tile (64 rows x 32 k), transposed into hs[k][m]
        #pragma unroll
        for (int l = 0; l < 2; ++l) {
            int fid = tid + l * 256;
            int r = fid >> 3, ck = fid & 7;
            float4 v = *(const float4*)(h_prev + (m0 + r) * GHID + k0 + ck * 4);
            hs[(ck * 4 + 0) * 68 + r] = v.x;
            hs[(ck * 4 + 1) * 68 + r] = v.y;
            hs[(ck * 4 + 2) * 68 + r] = v.z;
            hs[(ck * 4 + 3) * 68 + r] = v.w;
        }
        // stage weight tiles (3 gates x 32 n x 32 k), transposed into wsm[g][k][n]
        {
            int jn = tid >> 3, ck = tid & 7;
            #pragma unroll
            for (int g = 0; g < 3; ++g) {
                float4 v = *(const float4*)(w_hh + (size_t)(g * GHID + n0 + jn) * GHID + k0 + ck * 4);
                wsm[g][(ck * 4 + 0) * 34 + jn] = v.x;
                wsm[g][(ck * 4 + 1) * 34 + jn] = v.y;
                wsm[g][(ck * 4 + 2) * 34 + jn] = v.z;
                wsm[g][(ck * 4 + 3) * 34 + jn] = v.w;
            }
        }
        __syncthreads();
        #pragma unroll 8
        for (int kk = 0; kk < 32; ++kk) {
            float4 hv = *(const float4*)(&hs[kk * 68 + tm * 4]);
            #pragma unroll
            for (int g = 0; g < 3; ++g) {
                float2 wv = *(const float2*)(&wsm[g][kk * 34 + tn * 2]);
                accH[g][0][0] += hv.x * wv.x; accH[g][0][1] += hv.x * wv.y;
                accH[g][1][0] += hv.y * wv.x; accH[g][1][1] += hv.y * wv.y;
                accH[g][2][0] += hv.z * wv.x; accH[g][2][1] += hv.z * wv.y;
                accH[g][3][0] += hv.w * wv.x; accH[g][3][1] += hv.w * wv.y;
            }
        }
        __syncthreads();
    }

    // tail: h_t (42-wide) x w_ih[:, :42]  (L1/L2-cached reads)
    {
        const float* htp = ht + (m0 + tm * 4) * 42;
        for (int k = 0; k < 42; ++k) {
            float h0 = htp[k], h1 = htp[42 + k], h2 = htp[84 + k], h3 = htp[126 + k];
            #pragma unroll
            for (int g = 0; g < 3; ++g) {
                float w0 = w_ih[(g * GHID + n0 + tn * 2 + 0) * 63 + k];
                float w1 = w_ih[(g * GHID + n0 + tn * 2 + 1) * 63 + k];
                accI[g][0][0] += h0 * w0; accI[g][0][1] += h0 * w1;
                accI[g][1][0] += h1 * w0; accI[g][1][1] += h1 * w1;
                accI[g][2][0] += h2 * w0; accI[g][2][1] += h2 * w1;
                accI[g][3][0] += h3 * w0; accI[g][3][1] += h3 * w1;
            }
        }
    }

    // epilogue: gate math + h_new
    #pragma unroll
    for (int rr = 0; rr < 4; ++rr) {
        int bb = m0 + tm * 4 + rr;
        int e = idx[bb];
        const float* tb = table + e * 1536;
        float res[2];
        #pragma unroll
        for (int cc = 0; cc < 2; ++cc) {
            int col = n0 + tn * 2 + cc;
            float hr = accH[0][rr][cc] + b_hh[col];
            float hz = accH[1][rr][cc] + b_hh[GHID + col];
            float hn = accH[2][rr][cc] + b_hh[2 * GHID + col];
            float ir = accI[0][rr][cc] + tb[col];
            float iz = accI[1][rr][cc] + tb[GHID + col];
            float in_ = accI[2][rr][cc] + tb[2 * GHID + col];
            float rg = 1.f / (1.f + expf(-(ir + hr)));
            float zg = 1.f / (1.f + expf(-(iz + hz)));
            float ng = tanhf(in_ + rg * hn);
            float hp = h_prev[bb * GHID + col];
            res[cc] = (1.f - zg) * ng + zg * hp;
        }
        float2 outv; outv.x = res[0]; outv.y = res[1];
        *(float2*)(h_new + bb * GHID + n0 + tn * 2) = outv;
    }
}

// ====================== logits + argmax (one wave per row) ==================
__global__ __launch_bounds__(256) void gru_logits(
    const float* __restrict__ h_new, const float* __restrict__ w_out,
    const float* __restrict__ b_out, float* __restrict__ out,
    int* __restrict__ idx, int t)
{
    const int wave = threadIdx.x >> 6, lane = threadIdx.x & 63;
    const int b = blockIdx.x * 4 + wave;

    const float* hp = h_new + b * GHID + lane * 8;
    float hv[8];
    #pragma unroll
    for (int j = 0; j < 8; ++j) hv[j] = hp[j];

    float acc[NC];
    #pragma unroll
    for (int c = 0; c < NC; ++c) {
        const float* wr = w_out + c * GHID + lane * 8;
        float s = 0.f;
        #pragma unroll
        for (int j = 0; j < 8; ++j) s += hv[j] * wr[j];
        acc[c] = s;
    }
    #pragma unroll
    for (int off = 32; off > 0; off >>= 1) {
        #pragma unroll
        for (int c = 0; c < NC; ++c) acc[c] += __shfl_xor(acc[c], off);
    }
    float best = -1e30f; int bi = 0;
    #pragma unroll
    for (int c = 0; c < NC; ++c) {
        acc[c] += b_out[c];
        if (acc[c] > best) { best = acc[c]; bi = c; }   // strict > keeps first max
    }
    if (t < REAL_NL && lane < NC)
        out[(size_t)b * (REAL_NL * NC) + t * NC + lane] = acc[lane];
    if (lane == 0) idx[b] = bi;
}

// ============================================================================
extern "C" void kernel_launch(void* const* d_in, const int* in_sizes, int n_in,
                              void* d_out, int out_size, void* d_ws, size_t ws_size,
                              hipStream_t stream)
{
    const float* z    = (const float*)d_in[1];
    const float* dW   = (const float*)d_in[3];
    const float* db   = (const float*)d_in[4];
    const float* W0   = (const float*)d_in[5];
    const float* g0   = (const float*)d_in[6];
    const float* bb0  = (const float*)d_in[7];
    const float* m0   = (const float*)d_in[8];
    const float* v0   = (const float*)d_in[9];
    const float* al0  = (const float*)d_in[10];
    const float* W1   = (const float*)d_in[11];
    const float* g1   = (const float*)d_in[12];
    const float* bb1  = (const float*)d_in[13];
    const float* m1   = (const float*)d_in[14];
    const float* v1   = (const float*)d_in[15];
    const float* al1  = (const float*)d_in[16];
    const float* W2   = (const float*)d_in[17];
    const float* g2   = (const float*)d_in[18];
    const float* bb2  = (const float*)d_in[19];
    const float* m2   = (const float*)d_in[20];
    const float* v2   = (const float*)d_in[21];
    const float* al2  = (const float*)d_in[22];
    const float* w_px = (const float*)d_in[23];
    const float* b_px = (const float*)d_in[24];
    const float* w_ih = (const float*)d_in[25];
    const float* w_hh = (const float*)d_in[26];
    const float* b_ih = (const float*)d_in[27];
    const float* b_hh = (const float*)d_in[28];
    const float* w_out= (const float*)d_in[29];
    const float* b_out= (const float*)d_in[30];
    float* out = (float*)d_out;

    // workspace carve-up (all fp32): hseq | hA | hB | table | idx
    float* ws    = (float*)d_ws;
    float* hseq  = ws;                                      // 504*2048*42
    float* hA    = hseq + (size_t)NLFULL * BATCH * 42;      // 2048*512
    float* hB    = hA + (size_t)BATCH * GHID;               // 2048*512
    float* table = hB + (size_t)BATCH * GHID;               // 22*1536
    int*   idx   = (int*)(table + 22 * 1536);               // 2048

    upsample_kernel<<<dim3(BATCH, 4), 512, 0, stream>>>(
        z, dW, db,
        W0, g0, bb0, m0, v0, al0,
        W1, g1, bb1, m1, v1, al1,
        W2, g2, bb2, m2, v2, al2,
        hseq);

    table_kernel<<<(22 * 1536 + 255) / 256, 256, 0, stream>>>(w_px, b_px, w_ih, b_ih, table);
    init_kernel<<<(BATCH * GHID + 255) / 256, 256, 0, stream>>>(hA, idx);

    for (int t = 0; t < NLFULL; ++t) {
        const float* hp = (t & 1) ? hB : hA;
        float* hn       = (t & 1) ? hA : hB;
        gru_gates<<<dim3(16, 32), 256, 0, stream>>>(
            hp, hseq + (size_t)t * BATCH * 42, idx, table, w_hh, w_ih, b_hh, hn);
        gru_logits<<<512, 256, 0, stream>>>(hn, w_out, b_out, out, idx, t);
    }
}

// Round 3
// 38527.811 us; speedup vs baseline: 1.3937x; 1.3937x over previous
//
#include <hip/hip_runtime.h>
#include <math.h>

#define NLFULL 504
#define REAL_NL 500
#define BATCH 2048
#define NZ 50
#define NC 21
#define GHID 512
#define EPSB 1e-5f

typedef __attribute__((ext_vector_type(4))) float f32x4;
typedef __attribute__((ext_vector_type(8))) short short8;

__device__ __forceinline__ unsigned short f2bf(float x) {
    unsigned u = __builtin_bit_cast(unsigned, x);
    unsigned r = (u + 0x7FFFu + ((u >> 16) & 1u)) >> 16;
    return (unsigned short)r;
}
__device__ __forceinline__ float bf2f(unsigned short h) {
    unsigned u = ((unsigned)h) << 16;
    return __builtin_bit_cast(float, u);
}

// =============================== upsample ==================================
__global__ __launch_bounds__(512) void upsample_kernel(
    const float* __restrict__ z, const float* __restrict__ dW, const float* __restrict__ db,
    const float* __restrict__ W0, const float* __restrict__ g0, const float* __restrict__ bb0,
    const float* __restrict__ m0, const float* __restrict__ v0, const float* __restrict__ al0,
    const float* __restrict__ W1, const float* __restrict__ g1, const float* __restrict__ bb1,
    const float* __restrict__ m1, const float* __restrict__ v1, const float* __restrict__ al1,
    const float* __restrict__ W2, const float* __restrict__ g2, const float* __restrict__ bb2,
    const float* __restrict__ m2, const float* __restrict__ v2, const float* __restrict__ al2,
    float* __restrict__ hseq)
{
    __shared__ float bufA[5712];   // u: [336][17]   then w: [84][65]
    __shared__ float bufB[5544];   // v: [168][33]
    __shared__ float zl[52];

    const int b   = blockIdx.x;
    const int ta  = blockIdx.y * 16;
    const int nt0 = min(16, 63 - ta);
    const int tid = threadIdx.x;

    if (tid < NZ) zl[tid] = z[b * NZ + tid];
    __syncthreads();

    for (int i = tid; i < 336 * nt0; i += 512) {
        int c = i % 336, tt = i / 336;
        int row = c * 63 + ta + tt;
        const float* wr = dW + (size_t)row * NZ;
        float s = db[row];
        #pragma unroll
        for (int n = 0; n < NZ; ++n) s += zl[n] * wr[n];
        bufA[c * 17 + tt] = s;
    }
    __syncthreads();

    const float a0 = al0[0], a1 = al1[0], a2 = al2[0];

    for (int i = tid; i < 168 * 2 * nt0; i += 512) {
        int o = i % 168, tt1 = i / 168;
        int tt = tt1 >> 1, k = tt1 & 1;
        const float* wp = W0 + o * 2 + k;
        float s = 0.f;
        for (int c = 0; c < 336; ++c) s += bufA[c * 17 + tt] * wp[c * 336];
        float sc = g0[o] / sqrtf(v0[o] + EPSB);
        s = (s - m0[o]) * sc + bb0[o];
        s = (s >= 0.f) ? s : a0 * s;
        bufB[o * 33 + tt1] = s;
    }
    __syncthreads();

    for (int i = tid; i < 84 * 4 * nt0; i += 512) {
        int o = i % 84, tt2 = i / 84;
        int tt1 = tt2 >> 1, k = tt2 & 1;
        const float* wp = W1 + o * 2 + k;
        float s = 0.f;
        for (int c = 0; c < 168; ++c) s += bufB[c * 33 + tt1] * wp[c * 168];
        float sc = g1[o] / sqrtf(v1[o] + EPSB);
        s = (s - m1[o]) * sc + bb1[o];
        s = (s >= 0.f) ? s : a1 * s;
        bufA[o * 65 + tt2] = s;
    }
    __syncthreads();

    for (int i = tid; i < 42 * 8 * nt0; i += 512) {
        int o = i % 42, tt3 = i / 42;
        int tt2 = tt3 >> 1, k = tt3 & 1;
        const float* wp = W2 + o * 2 + k;
        float s = 0.f;
        for (int c = 0; c < 84; ++c) s += bufA[c * 65 + tt2] * wp[c * 84];
        float sc = g2[o] / sqrtf(v2[o] + EPSB);
        s = (s - m2[o]) * sc + bb2[o];
        s = (s >= 0.f) ? s : a2 * s;
        int t3 = 8 * ta + tt3;
        hseq[(size_t)t3 * (BATCH * 42) + b * 42 + o] = s;
    }
}

// ================= table: gi-contribution of one-hot px =====================
__global__ void table_kernel(const float* __restrict__ w_px, const float* __restrict__ b_px,
                             const float* __restrict__ w_ih, const float* __restrict__ b_ih,
                             float* __restrict__ table)
{
    int i = blockIdx.x * 256 + threadIdx.x;
    if (i >= 22 * 1536) return;
    int e = i / 1536, jg = i % 1536;
    const float* wih = w_ih + jg * 63 + 42;
    float s = b_ih[jg];
    #pragma unroll
    for (int jp = 0; jp < NC; ++jp) {
        float px = b_px[jp] + (e < NC ? w_px[jp * NC + e] : 0.f);
        s += px * wih[jp];
    }
    table[i] = s;
}

// ============ pack weights into MFMA B-fragment order, 3 bf16 limbs =========
// whh pack layout: [g][nf(32)][kf(16)][lane(64)*8]
// B-frag: lane l supplies B[k=(l>>4)*8+e][n=l&15] = w[n][k]
__global__ void pack_whh_kernel(const float* __restrict__ w_hh,
                                unsigned short* __restrict__ pH,
                                unsigned short* __restrict__ pM,
                                unsigned short* __restrict__ pL)
{
    int i = blockIdx.x * 256 + threadIdx.x;
    if (i >= 3 * 32 * 16 * 512) return;
    int e = i & 7, l = (i >> 3) & 63, kf = (i >> 9) & 15, nf = (i >> 13) & 31, g = i >> 18;
    int n = nf * 16 + (l & 15);
    int k = kf * 32 + ((l >> 4) << 3) + e;
    float v = w_hh[(size_t)(g * GHID + n) * GHID + k];
    unsigned short h1 = f2bf(v);       float r1 = v - bf2f(h1);
    unsigned short h2 = f2bf(r1);      float r2 = r1 - bf2f(h2);
    unsigned short h3 = f2bf(r2);
    pH[i] = h1; pM[i] = h2; pL[i] = h3;
}

// wih pack layout: [g][nf(32)][kf(2)][lane(64)*8], K padded 42 -> 64 with zeros
__global__ void pack_wih_kernel(const float* __restrict__ w_ih,
                                unsigned short* __restrict__ pH,
                                unsigned short* __restrict__ pM,
                                unsigned short* __restrict__ pL)
{
    int i = blockIdx.x * 256 + threadIdx.x;
    if (i >= 3 * 32 * 2 * 512) return;
    int e = i & 7, l = (i >> 3) & 63, kf = (i >> 9) & 1, nf = (i >> 10) & 31, g = i >> 15;
    int n = nf * 16 + (l & 15);
    int k = kf * 32 + ((l >> 4) << 3) + e;
    float v = (k < 42) ? w_ih[(size_t)(g * GHID + n) * 63 + k] : 0.f;
    unsigned short h1 = f2bf(v);       float r1 = v - bf2f(h1);
    unsigned short h2 = f2bf(r1);      float r2 = r1 - bf2f(h2);
    unsigned short h3 = f2bf(r2);
    pH[i] = h1; pM[i] = h2; pL[i] = h3;
}

// ===================== init h0 (3 bf16 limbs), idx ==========================
__global__ void init_kernel(unsigned short* __restrict__ hH, unsigned short* __restrict__ hM,
                            unsigned short* __restrict__ hL, int* __restrict__ idx)
{
    int i = blockIdx.x * 256 + threadIdx.x;
    if (i < BATCH * GHID) { hH[i] = 0; hM[i] = 0; hL[i] = 0; }
    if (i < BATCH) idx[i] = NC;
}

// ===================== GRU gates (MFMA, 3-limb / 6-product) =================
// wave-tile 32M x 32N x 3 gates; block = 2 waves (64M); grid (32, 16).
// acc += aH*bH + aH*bM + aM*bH + aH*bL + aL*bH + aM*bM   (error ~2^-24)
#define MFMA6(acc, aH_, aM_, aL_, bH_, bM_, bL_)                                  \
    acc = __builtin_amdgcn_mfma_f32_16x16x32_bf16(aH_, bH_, acc, 0, 0, 0);        \
    acc = __builtin_amdgcn_mfma_f32_16x16x32_bf16(aH_, bM_, acc, 0, 0, 0);        \
    acc = __builtin_amdgcn_mfma_f32_16x16x32_bf16(aM_, bH_, acc, 0, 0, 0);        \
    acc = __builtin_amdgcn_mfma_f32_16x16x32_bf16(aH_, bL_, acc, 0, 0, 0);        \
    acc = __builtin_amdgcn_mfma_f32_16x16x32_bf16(aL_, bH_, acc, 0, 0, 0);        \
    acc = __builtin_amdgcn_mfma_f32_16x16x32_bf16(aM_, bM_, acc, 0, 0, 0);

__global__ __launch_bounds__(128) void gru_gates_mfma(
    const unsigned short* __restrict__ hpH, const unsigned short* __restrict__ hpM,
    const unsigned short* __restrict__ hpL,
    const float* __restrict__ ht,   // hseq + t*B*42
    const int* __restrict__ idx, const float* __restrict__ table,
    const unsigned short* __restrict__ whhH, const unsigned short* __restrict__ whhM,
    const unsigned short* __restrict__ whhL,
    const unsigned short* __restrict__ wihH, const unsigned short* __restrict__ wihM,
    const unsigned short* __restrict__ wihL,
    const float* __restrict__ b_hh,
    unsigned short* __restrict__ hnH, unsigned short* __restrict__ hnM,
    unsigned short* __restrict__ hnL)
{
    const int l  = threadIdx.x & 63;
    const int wv = threadIdx.x >> 6;
    const int m0 = blockIdx.x * 64 + wv * 32;
    const int nf0 = blockIdx.y * 2;
    const int lrow = l & 15;
    const int lk = (l >> 4) << 3;

    f32x4 accRZ[2][2][2];   // [r|z][mi][ni]
    f32x4 accIN[2][2];      // n-gate, input part
    f32x4 accHN[2][2];      // n-gate, hidden part
    #pragma unroll
    for (int a = 0; a < 2; ++a)
        #pragma unroll
        for (int b = 0; b < 2; ++b) {
            accRZ[0][a][b] = (f32x4)0.f; accRZ[1][a][b] = (f32x4)0.f;
            accIN[a][b] = (f32x4)0.f;    accHN[a][b] = (f32x4)0.f;
        }

    const size_t arow0 = (size_t)(m0 + lrow) * GHID + lk;
    const size_t arow1 = arow0 + 16 * GHID;

    // ---- H part: K = 512 = 16 k-frags ----
    for (int kf = 0; kf < 16; ++kf) {
        short8 aH[2], aM[2], aL[2];
        aH[0] = *(const short8*)(hpH + arow0 + kf * 32);
        aM[0] = *(const short8*)(hpM + arow0 + kf * 32);
        aL[0] = *(const short8*)(hpL + arow0 + kf * 32);
        aH[1] = *(const short8*)(hpH + arow1 + kf * 32);
        aM[1] = *(const short8*)(hpM + arow1 + kf * 32);
        aL[1] = *(const short8*)(hpL + arow1 + kf * 32);
        #pragma unroll
        for (int g = 0; g < 3; ++g) {
            #pragma unroll
            for (int ni = 0; ni < 2; ++ni) {
                size_t boff = ((size_t)((g * 32 + nf0 + ni) * 16 + kf) << 9) + (l << 3);
                short8 bH = *(const short8*)(whhH + boff);
                short8 bM = *(const short8*)(whhM + boff);
                short8 bL = *(const short8*)(whhL + boff);
                #pragma unroll
                for (int mi = 0; mi < 2; ++mi) {
                    f32x4* acc = (g == 2) ? &accHN[mi][ni] : &accRZ[g][mi][ni];
                    MFMA6((*acc), aH[mi], aM[mi], aL[mi], bH, bM, bL);
                }
            }
        }
    }

    // ---- I part: K = 42 (2 k-frags, on-the-fly fp32 -> 3-limb split) ----
    #pragma unroll
    for (int kf = 0; kf < 2; ++kf) {
        short8 aH[2], aM[2], aL[2];
        #pragma unroll
        for (int mi = 0; mi < 2; ++mi) {
            const float* rp = ht + (size_t)(m0 + mi * 16 + lrow) * 42;
            #pragma unroll
            for (int e = 0; e < 8; ++e) {
                int k = kf * 32 + lk + e;
                float f = (k < 42) ? rp[k] : 0.f;
                unsigned short h1 = f2bf(f);  float r1 = f - bf2f(h1);
                unsigned short h2 = f2bf(r1); float r2 = r1 - bf2f(h2);
                aH[mi][e] = (short)h1;
                aM[mi][e] = (short)h2;
                aL[mi][e] = (short)f2bf(r2);
            }
        }
        #pragma unroll
        for (int g = 0; g < 3; ++g) {
            #pragma unroll
            for (int ni = 0; ni < 2; ++ni) {
                size_t boff = ((size_t)((g * 32 + nf0 + ni) * 2 + kf) << 9) + (l << 3);
                short8 bH = *(const short8*)(wihH + boff);
                short8 bM = *(const short8*)(wihM + boff);
                short8 bL = *(const short8*)(wihL + boff);
                #pragma unroll
                for (int mi = 0; mi < 2; ++mi) {
                    f32x4* acc = (g == 2) ? &accIN[mi][ni] : &accRZ[g][mi][ni];
                    MFMA6((*acc), aH[mi], aM[mi], aL[mi], bH, bM, bL);
                }
            }
        }
    }

    // ---- epilogue: D layout row=(l>>4)*4+r, col=l&15 ----
    #pragma unroll
    for (int ni = 0; ni < 2; ++ni) {
        int c = (nf0 + ni) * 16 + lrow;
        float bhr = b_hh[c], bhz = b_hh[GHID + c], bhn = b_hh[2 * GHID + c];
        #pragma unroll
        for (int mi = 0; mi < 2; ++mi) {
            #pragma unroll
            for (int r = 0; r < 4; ++r) {
                int m = m0 + mi * 16 + ((l >> 4) << 2) + r;
                const float* tb = table + idx[m] * 1536;
                float rv = accRZ[0][mi][ni][r] + bhr + tb[c];
                float zv = accRZ[1][mi][ni][r] + bhz + tb[GHID + c];
                float rg = 1.f / (1.f + expf(-rv));
                float zg = 1.f / (1.f + expf(-zv));
                float nv = accIN[mi][ni][r] + tb[2 * GHID + c] + rg * (accHN[mi][ni][r] + bhn);
                float ng = tanhf(nv);
                size_t off = (size_t)m * GHID + c;
                float hpv = bf2f(hpH[off]) + bf2f(hpM[off]) + bf2f(hpL[off]);
                float hnv = (1.f - zg) * ng + zg * hpv;
                unsigned short h1 = f2bf(hnv);  float r1 = hnv - bf2f(h1);
                unsigned short h2 = f2bf(r1);   float r2 = r1 - bf2f(h2);
                hnH[off] = h1;
                hnM[off] = h2;
                hnL[off] = f2bf(r2);
            }
        }
    }
}

// ====================== logits + argmax (one wave per row) ==================
__global__ __launch_bounds__(256) void gru_logits(
    const unsigned short* __restrict__ hH, const unsigned short* __restrict__ hM,
    const unsigned short* __restrict__ hL,
    const float* __restrict__ w_out, const float* __restrict__ b_out,
    float* __restrict__ out, int* __restrict__ idx, int t)
{
    const int wave = threadIdx.x >> 6, lane = threadIdx.x & 63;
    const int b = blockIdx.x * 4 + wave;

    const size_t base = (size_t)b * GHID + lane * 8;
    float hv[8];
    #pragma unroll
    for (int j = 0; j < 8; ++j)
        hv[j] = bf2f(hH[base + j]) + bf2f(hM[base + j]) + bf2f(hL[base + j]);

    float acc[NC];
    #pragma unroll
    for (int c = 0; c < NC; ++c) {
        const float* wr = w_out + c * GHID + lane * 8;
        float s = 0.f;
        #pragma unroll
        for (int j = 0; j < 8; ++j) s += hv[j] * wr[j];
        acc[c] = s;
    }
    #pragma unroll
    for (int off = 32; off > 0; off >>= 1) {
        #pragma unroll
        for (int c = 0; c < NC; ++c) acc[c] += __shfl_xor(acc[c], off);
    }
    float best = -1e30f; int bi = 0;
    #pragma unroll
    for (int c = 0; c < NC; ++c) {
        acc[c] += b_out[c];
        if (acc[c] > best) { best = acc[c]; bi = c; }   // strict > keeps first max
    }
    if (t < REAL_NL && lane < NC)
        out[(size_t)b * (REAL_NL * NC) + t * NC + lane] = acc[lane];
    if (lane == 0) idx[b] = bi;
}

// ============================================================================
extern "C" void kernel_launch(void* const* d_in, const int* in_sizes, int n_in,
                              void* d_out, int out_size, void* d_ws, size_t ws_size,
                              hipStream_t stream)
{
    const float* z    = (const float*)d_in[1];
    const float* dW   = (const float*)d_in[3];
    const float* db   = (const float*)d_in[4];
    const float* W0   = (const float*)d_in[5];
    const float* g0   = (const float*)d_in[6];
    const float* bb0  = (const float*)d_in[7];
    const float* m0   = (const float*)d_in[8];
    const float* v0   = (const float*)d_in[9];
    const float* al0  = (const float*)d_in[10];
    const float* W1   = (const float*)d_in[11];
    const float* g1   = (const float*)d_in[12];
    const float* bb1  = (const float*)d_in[13];
    const float* m1   = (const float*)d_in[14];
    const float* v1   = (const float*)d_in[15];
    const float* al1  = (const float*)d_in[16];
    const float* W2   = (const float*)d_in[17];
    const float* g2   = (const float*)d_in[18];
    const float* bb2  = (const float*)d_in[19];
    const float* m2   = (const float*)d_in[20];
    const float* v2   = (const float*)d_in[21];
    const float* al2  = (const float*)d_in[22];
    const float* w_px = (const float*)d_in[23];
    const float* b_px = (const float*)d_in[24];
    const float* w_ih = (const float*)d_in[25];
    const float* w_hh = (const float*)d_in[26];
    const float* b_ih = (const float*)d_in[27];
    const float* b_hh = (const float*)d_in[28];
    const float* w_out= (const float*)d_in[29];
    const float* b_out= (const float*)d_in[30];
    float* out = (float*)d_out;

    // ws: hseq(f32) | hA 3-limb | hB 3-limb | whh 3-limb | wih 3-limb | table | idx
    float* ws = (float*)d_ws;
    float* hseq = ws;                                           // 504*2048*42 f32
    unsigned short* hAH = (unsigned short*)(hseq + (size_t)NLFULL * BATCH * 42);
    unsigned short* hAM = hAH + (size_t)BATCH * GHID;
    unsigned short* hAL = hAM + (size_t)BATCH * GHID;
    unsigned short* hBH = hAL + (size_t)BATCH * GHID;
    unsigned short* hBM = hBH + (size_t)BATCH * GHID;
    unsigned short* hBL = hBM + (size_t)BATCH * GHID;
    unsigned short* whhH = hBL + (size_t)BATCH * GHID;          // 3*32*16*512
    unsigned short* whhM = whhH + 3 * 32 * 16 * 512;
    unsigned short* whhL = whhM + 3 * 32 * 16 * 512;
    unsigned short* wihH = whhL + 3 * 32 * 16 * 512;            // 3*32*2*512
    unsigned short* wihM = wihH + 3 * 32 * 2 * 512;
    unsigned short* wihL = wihM + 3 * 32 * 2 * 512;
    float* table = (float*)(wihL + 3 * 32 * 2 * 512);           // 22*1536
    int*   idx   = (int*)(table + 22 * 1536);                   // 2048

    upsample_kernel<<<dim3(BATCH, 4), 512, 0, stream>>>(
        z, dW, db,
        W0, g0, bb0, m0, v0, al0,
        W1, g1, bb1, m1, v1, al1,
        W2, g2, bb2, m2, v2, al2,
        hseq);

    table_kernel<<<(22 * 1536 + 255) / 256, 256, 0, stream>>>(w_px, b_px, w_ih, b_ih, table);
    pack_whh_kernel<<<(3 * 32 * 16 * 512 + 255) / 256, 256, 0, stream>>>(w_hh, whhH, whhM, whhL);
    pack_wih_kernel<<<(3 * 32 * 2 * 512 + 255) / 256, 256, 0, stream>>>(w_ih, wihH, wihM, wihL);
    init_kernel<<<(BATCH * GHID + 255) / 256, 256, 0, stream>>>(hAH, hAM, hAL, idx);

    for (int t = 0; t < NLFULL; ++t) {
        const unsigned short* pH = (t & 1) ? hBH : hAH;
        const unsigned short* pM = (t & 1) ? hBM : hAM;
        const unsigned short* pL = (t & 1) ? hBL : hAL;
        unsigned short* nH = (t & 1) ? hAH : hBH;
        unsigned short* nM = (t & 1) ? hAM : hBM;
        unsigned short* nL = (t & 1) ? hAL : hBL;
        gru_gates_mfma<<<dim3(32, 16), 128, 0, stream>>>(
            pH, pM, pL, hseq + (size_t)t * BATCH * 42, idx, table,
            whhH, whhM, whhL, wihH, wihM, wihL, b_hh, nH, nM, nL);
        gru_logits<<<512, 256, 0, stream>>>(nH, nM, nL, w_out, b_out, out, idx, t);
    }
}